// Round 15
// baseline (10125.673 us; speedup 1.0000x reference)
//
#include <hip/hip_runtime.h>

#define HID 768
#define EMB 512
#define NG  64
#define FIN 5
#define NL  16
#define CB  384   // column block width (HID/2)
#define PSEG 16   // pooling segments per graph
#define WPSEG 16  // make_wp1 segments

typedef _Float16 f16;
typedef f16   f16x4 __attribute__((ext_vector_type(4)));
typedef f16   f16x8 __attribute__((ext_vector_type(8)));
typedef float f32x4 __attribute__((ext_vector_type(4)));

// ---------------- CSR build ----------------
__global__ void count_deg_k(const int* __restrict__ ei, int* __restrict__ deg, int E) {
    int e = blockIdx.x * 256 + threadIdx.x;
    if (e < E) atomicAdd(&deg[ei[E + e]], 1);
}

// batch is sorted: goff[g] = lower_bound(batch, g); no atomics
__global__ void goff_k(const int* __restrict__ batch, int* __restrict__ goff, int n) {
    int g = threadIdx.x;
    if (g > NG) return;
    if (g == NG) { goff[NG] = n; return; }
    int lo = 0, hi = n;
    while (lo < hi) { int mid = (lo + hi) >> 1; if (batch[mid] < g) lo = mid + 1; else hi = mid; }
    goff[g] = lo;
}

__global__ void scan_rowptr_k(const int* __restrict__ deg, int* __restrict__ rp,
                              int* __restrict__ cur, int n) {
    __shared__ int wsum[16];
    __shared__ int carry;
    int t = threadIdx.x, lane = t & 63, w = t >> 6;
    if (t == 0) carry = 0;
    __syncthreads();
    for (int base = 0; base < n; base += 4096) {
        int v[4]; int s = 0;
        #pragma unroll
        for (int q = 0; q < 4; ++q) { int i = base + t * 4 + q; v[q] = (i < n) ? deg[i] : 0; s += v[q]; }
        int tot = s;
        int sc = tot;
        #pragma unroll
        for (int off = 1; off < 64; off <<= 1) { int u = __shfl_up(sc, off); if (lane >= off) sc += u; }
        if (lane == 63) wsum[w] = sc;
        __syncthreads();
        if (t < 16) {
            int xw = wsum[t];
            #pragma unroll
            for (int off = 1; off < 16; off <<= 1) { int u = __shfl_up(xw, off); if (t >= off) xw += u; }
            wsum[t] = xw;
        }
        __syncthreads();
        int woff = (w > 0) ? wsum[w - 1] : 0;
        int excl = carry + woff + sc - tot;
        #pragma unroll
        for (int q = 0; q < 4; ++q) { int i = base + t * 4 + q; if (i < n) { rp[i] = excl; cur[i] = excl; } excl += v[q]; }
        __syncthreads();
        if (t == 0) carry += wsum[15];
        __syncthreads();
    }
    if (t == 0) rp[n] = carry;
}

__global__ void scatter_k(const int* __restrict__ ei, int* __restrict__ cur,
                          int* __restrict__ csr, int E) {
    int e = blockIdx.x * 256 + threadIdx.x;
    if (e < E) { int d = ei[E + e]; int pos = atomicAdd(&cur[d], 1); csr[pos] = ei[e]; }
}

// canonicalize neighbor order (atomic scatter order varies call-to-call)
__global__ void sort_csr_k(const int* __restrict__ rp, int* __restrict__ csr, int n) {
    int i = blockIdx.x * 256 + threadIdx.x;
    if (i >= n) return;
    int e0 = rp[i], e1 = rp[i + 1];
    for (int a = e0 + 1; a < e1; ++a) {
        int v = csr[a];
        int b = a - 1;
        while (b >= e0 && csr[b] > v) { csr[b + 1] = csr[b]; --b; }
        csr[b + 1] = v;
    }
}

// ---- per-layer weight convert: W[k][n] fp32 -> wt[z][n][k] fp16 * 64 ----
__global__ void convert_layer_k(const float* __restrict__ Wa, const float* __restrict__ Wb,
                                f16* __restrict__ wt) {
    __shared__ float tile[64][65];
    const float* src = blockIdx.z ? Wb : Wa;
    f16* dst = wt + (size_t)blockIdx.z * HID * HID;
    int k0 = blockIdx.x * 64, n0 = blockIdx.y * 64;
    int t = threadIdx.x;
    #pragma unroll 4
    for (int i = 0; i < 16; ++i) {
        int r = (t >> 6) + i * 4;
        tile[r][t & 63] = src[(size_t)(k0 + r) * HID + n0 + (t & 63)];
    }
    __syncthreads();
    #pragma unroll 4
    for (int i = 0; i < 16; ++i) {
        int r = (t >> 6) + i * 4;
        dst[(size_t)(n0 + r) * HID + k0 + (t & 63)] = (f16)(tile[t & 63][r] * 64.0f);
    }
}

// ---- layer-0 folding, 2-stage deterministic ----
__global__ void make_wp1_part_k(const float* __restrict__ Wp, const float* __restrict__ bp,
                                const float* __restrict__ W1_0, float* __restrict__ part) {
    int nn = blockIdx.x * 256 + threadIdx.x;
    int s = blockIdx.y;
    if (nn >= HID) return;
    float acc[6] = {0, 0, 0, 0, 0, 0};
    int j0 = s * (HID / WPSEG), j1 = j0 + (HID / WPSEG);
    for (int j = j0; j < j1; ++j) {
        float wj = W1_0[(size_t)j * HID + nn];
        #pragma unroll
        for (int k = 0; k < FIN; ++k) acc[k] += Wp[k * HID + j] * wj;
        acc[5] += bp[j] * wj;
    }
    #pragma unroll
    for (int k = 0; k < 6; ++k) part[((size_t)s * 6 + k) * HID + nn] = acc[k];
}

__global__ void make_wp1_red_k(const float* __restrict__ part, float* __restrict__ wp1) {
    int nn = blockIdx.x * 256 + threadIdx.x;
    if (nn >= HID) return;
    #pragma unroll
    for (int k = 0; k < 6; ++k) {
        float a = 0.0f;
        #pragma unroll
        for (int s = 0; s < WPSEG; ++s) a += part[((size_t)s * 6 + k) * HID + nn];
        wp1[k * HID + nn] = a;
    }
}

__device__ __forceinline__ void row_scale(float amax, float& sc, float& rs) {
    int ex = 10;
    if (amax > 0.0f) frexpf(amax, &ex);
    int sh = 10 - ex;
    sh = sh > 120 ? 120 : (sh < -120 ? -120 : sh);
    sc = ldexpf(1.0f, sh);
    rs = ldexpf(1.0f, -sh);
}

// ---- fused layer0: z = relu(xagg@wp1 + (deg+1)*bpW1 + b1_0); writes 4 h-slots ----
__global__ __launch_bounds__(256) void fused_l0_k(
    const float* __restrict__ x, const int* __restrict__ rp, const int* __restrict__ csr,
    const float* __restrict__ wp1, const float* __restrict__ b1_0,
    f16* __restrict__ h00, f16* __restrict__ h01,   // col0: half0, half1
    f16* __restrict__ h10, f16* __restrict__ h11,   // col1: half0, half1
    float* __restrict__ rs_out, int nreal, int half) {
    __shared__ float w[7 * HID];
    for (int idx = threadIdx.x; idx < 7 * HID; idx += 256)
        w[idx] = (idx < 6 * HID) ? wp1[idx] : b1_0[idx - 6 * HID];
    __syncthreads();
    int node = blockIdx.x * 4 + (threadIdx.x >> 6);
    int lane = threadIdx.x & 63;
    int cblk = lane >> 5, ll = lane & 31;
    f16* base;
    int rloc;
    if (node < half) { base = cblk ? h10 : h00; rloc = node; }
    else             { base = cblk ? h11 : h01; rloc = node - half; }
    f16* orow = base + (size_t)rloc * CB + ll * 12;
    if (node >= nreal) {
        #pragma unroll
        for (int t = 0; t < 12; ++t) orow[t] = (f16)0.0f;
        if (lane == 0) rs_out[node] = 1.0f;
        return;
    }
    int e0 = rp[node], e1 = rp[node + 1];
    float xa[FIN];
    #pragma unroll
    for (int k = 0; k < FIN; ++k) xa[k] = x[(size_t)node * FIN + k];
    for (int e = e0; e < e1; ++e) {
        int j = csr[e];
        #pragma unroll
        for (int k = 0; k < FIN; ++k) xa[k] += x[(size_t)j * FIN + k];
    }
    float dp1 = (float)(e1 - e0 + 1);
    float a[12];
    #pragma unroll
    for (int t = 0; t < 12; ++t) {
        int c = lane * 12 + t;
        float v = w[5 * HID + c] * dp1 + w[6 * HID + c];
        #pragma unroll
        for (int k = 0; k < FIN; ++k) v += xa[k] * w[k * HID + c];
        a[t] = fmaxf(v, 0.0f);
    }
    float amax = 0.0f;
    #pragma unroll
    for (int t = 0; t < 12; ++t) amax = fmaxf(amax, fabsf(a[t]));
    #pragma unroll
    for (int off = 32; off; off >>= 1) amax = fmaxf(amax, __shfl_xor(amax, off));
    float sc, rs;
    row_scale(amax, sc, rs);
    if (lane == 0) rs_out[node] = rs;
    #pragma unroll
    for (int t = 0; t < 12; ++t) orow[t] = (f16)(a[t] * sc);
}

// ---- aggcol: one column block (2 row-half slots in, 2 out).
// computeScale=1 (col0 pass): also derive fresh per-row scale rsOut from amaxR inline ----
__global__ __launch_bounds__(256) void aggcol_k(
    const f16* __restrict__ s0, const f16* __restrict__ s1,
    f16* __restrict__ d0, f16* __restrict__ d1,
    const float* __restrict__ rsIn, float inShift,
    float* __restrict__ rsOut, const float* __restrict__ amaxR,
    const int* __restrict__ rp, const int* __restrict__ csr, int nreal, int half,
    int computeScale) {
    int node = blockIdx.x * 8 + (threadIdx.x >> 5);
    int l = threadIdx.x & 31;
    f16* orow = (node < half ? d0 + (size_t)node * CB : d1 + (size_t)(node - half) * CB) + l * 12;
    if (node >= nreal) {
        #pragma unroll
        for (int t = 0; t < 12; ++t) orow[t] = (f16)0.0f;
        if (computeScale && l == 0) rsOut[node] = 1.0f;
        return;
    }
    int e0 = rp[node], e1 = rp[node + 1];
    float invOut;
    if (computeScale) {
        float M = amaxR[node];
        for (int e = e0; e < e1; ++e) M = fmaxf(M, amaxR[csr[e]]);
        float r = 1.0f;
        if (M > 0.0f) {
            int ex; frexpf(M, &ex);
            int sh = ex - 9;                  // M / 2^sh in [256,512)
            sh = sh > 120 ? 120 : (sh < -120 ? -120 : sh);
            r = ldexpf(1.0f, sh);
        }
        if (l == 0) rsOut[node] = r;
        invOut = 1.0f / r;
    } else {
        invOut = 1.0f / rsOut[node];
    }
    float a[12];
    {
        float f = rsIn[node] * inShift * invOut;
        const f16* srow = (node < half ? s0 + (size_t)node * CB : s1 + (size_t)(node - half) * CB);
        const f16x4* p = (const f16x4*)(srow + l * 12);
        f16x4 v0 = p[0], v1 = p[1], v2 = p[2];
        #pragma unroll
        for (int t = 0; t < 4; ++t) {
            a[t] = (float)v0[t] * f; a[4 + t] = (float)v1[t] * f; a[8 + t] = (float)v2[t] * f;
        }
    }
    for (int e = e0; e < e1; ++e) {
        int j = csr[e];
        float f = rsIn[j] * inShift * invOut;
        const f16* srow = (j < half ? s0 + (size_t)j * CB : s1 + (size_t)(j - half) * CB);
        const f16x4* p = (const f16x4*)(srow + l * 12);
        f16x4 v0 = p[0], v1 = p[1], v2 = p[2];
        #pragma unroll
        for (int t = 0; t < 4; ++t) {
            a[t] += (float)v0[t] * f; a[4 + t] += (float)v1[t] * f; a[8 + t] += (float)v2[t] * f;
        }
    }
    f16x4 o0, o1, o2;
    #pragma unroll
    for (int t = 0; t < 4; ++t) {
        o0[t] = (f16)a[t]; o1[t] = (f16)a[4 + t]; o2[t] = (f16)a[8 + t];
    }
    f16x4* op = (f16x4*)orow;
    op[0] = o0; op[1] = o1; op[2] = o2;
}

// ---- GEMM: 128x128 tile, BK=64. A: global_load_lds double-buffer (32 KB LDS).
// B: registers direct from L2-resident wt (no LDS), loaded end-of-step for t+1.
// LDS total 34.8 KB + VGPR<=170 -> 3 blocks/CU (12 waves). Steady FIFO at step top
// = [A(t):4, B(t):8]; explicit vmcnt(8) drains A(t) (cross-wave via barrier);
// B(t) drained by compiler-inserted counts inside the MFMA cluster.
// T2 involution swizzle on A, T5 setprio, XCD-swizzled flat grid, LDS-staged C. ----
__global__ __launch_bounds__(256, 3) void gemm_seg_k(
    const f16* __restrict__ a0, const f16* __restrict__ a1,
    f16* __restrict__ c0, f16* __restrict__ c1,
    const float* __restrict__ rs, int rsOff, float shiftIn,
    const f16* __restrict__ wt, const float* __restrict__ bias,
    float* __restrict__ amaxR, int recAmax) {
    __shared__ f16 lds[17408];            // Abuf0 @0, Abuf1 @8192 (f16); epilogue cst 128x136
    const int tid = threadIdx.x;
    const int lane = tid & 63;
    const int wid = tid >> 6;

    // bijective XCD swizzle (ERRATA #11 form), n-fastest within chunk
    const int nwg = gridDim.x;
    const int q = nwg >> 3, r = nwg & 7;
    const int xcd = blockIdx.x & 7, loc = blockIdx.x >> 3;
    const int id2 = (xcd < r ? xcd * (q + 1) : r * (q + 1) + (xcd - r) * q) + loc;
    const int m0 = (id2 / 6) * 128;
    const int n0 = (id2 % 6) * 128;

    const int wr = (wid >> 1) * 64;
    const int wc = (wid & 1) * 64;
    const int lrow = lane >> 3;                 // 0..7
    const int usrc = (lane & 7) ^ lrow;         // inverse-swizzled 16B unit for staging src
    const int l15 = lane & 15, l4 = lane >> 4;

    auto stageA = [&](int kt, int buf) {
        const f16* abase = (kt < 6) ? a0 : a1;
        const int kb = (kt < 6 ? kt : kt - 6) * 64;
        f16* As = lds + buf * 8192;
        #pragma unroll
        for (int i = 0; i < 4; ++i) {
            int chunk = i * 4 + wid;            // wave-uniform
            int row = chunk * 8 + lrow;
            const f16* ga = abase + (size_t)(m0 + row) * CB + kb + usrc * 8;
            __builtin_amdgcn_global_load_lds(
                (const __attribute__((address_space(1))) void*)ga,
                (__attribute__((address_space(3))) void*)(As + chunk * 512), 16, 0, 0);
        }
    };

    f16x8 bfr[4][2];
    auto loadB = [&](int kt) {
        #pragma unroll
        for (int n = 0; n < 4; ++n)
            #pragma unroll
            for (int kk = 0; kk < 2; ++kk)
                bfr[n][kk] = *(const f16x8*)(wt + (size_t)(n0 + wc + n * 16 + l15) * HID
                                             + kt * 64 + (kk * 4 + l4) * 8);
    };

    f32x4 acc[4][4];
    #pragma unroll
    for (int m = 0; m < 4; ++m)
        #pragma unroll
        for (int n = 0; n < 4; ++n) acc[m][n] = (f32x4){0.f, 0.f, 0.f, 0.f};

    // prologue: FIFO [A(0):4, B(0):8]
    stageA(0, 0);
    loadB(0);

    #pragma unroll
    for (int t = 0; t < 12; ++t) {
        // drain A(t) (oldest 4); leave B(t) (compiler waits it inside the cluster)
        asm volatile("s_waitcnt vmcnt(8)" ::: "memory");
        __builtin_amdgcn_s_barrier();
        __builtin_amdgcn_sched_barrier(0);
        // stage A(t+1): its buffer's step-(t-1) readers all crossed the barrier above
        if (t < 11) stageA(t + 1, (t + 1) & 1);
        // A fragments (swizzled ds_read from Abuf[t&1])
        const f16* Ac = lds + (t & 1) * 8192;
        f16x8 af[4][2];
        #pragma unroll
        for (int m = 0; m < 4; ++m) {
            int rowH = wr + m * 16 + l15;
            int sw = rowH & 7;
            #pragma unroll
            for (int kk = 0; kk < 2; ++kk) {
                int u = kk * 4 + l4;
                af[m][kk] = *(const f16x8*)(Ac + rowH * 64 + ((u ^ sw) << 3));
            }
        }
        __builtin_amdgcn_s_setprio(1);
        #pragma unroll
        for (int kk = 0; kk < 2; ++kk)
            #pragma unroll
            for (int m = 0; m < 4; ++m)
                #pragma unroll
                for (int n = 0; n < 4; ++n)
                    acc[m][n] = __builtin_amdgcn_mfma_f32_16x16x32_f16(af[m][kk], bfr[n][kk], acc[m][n], 0, 0, 0);
        __builtin_amdgcn_s_setprio(0);
        // B(t+1) into regs (deps force this after bfr's last read above)
        if (t < 11) loadB(t + 1);
    }
    __syncthreads();

    // ---- epilogue: per-lane row scales (registers), bias+relu+amax, stage C in LDS
    // [128][136], coalesced f16x8 stores ----
    float rvv[16], rinvv[16];
    #pragma unroll
    for (int m = 0; m < 4; ++m)
        #pragma unroll
        for (int r2 = 0; r2 < 4; ++r2) {
            int rowB = wr + m * 16 + (l4 << 2) + r2;
            float rv = rs[rsOff + m0 + rowB] * shiftIn * 8.0f;
            rvv[m * 4 + r2] = rv;
            rinvv[m * 4 + r2] = 1.0f / rv;
        }
    f16* cst = lds;   // aliases A buffers; safe after barrier
    float am[16];
    #pragma unroll
    for (int i = 0; i < 16; ++i) am[i] = 0.0f;
    #pragma unroll
    for (int n = 0; n < 4; ++n) {
        const int colB = wc + n * 16 + l15;
        const float bcol = bias[n0 + colB];
        #pragma unroll
        for (int m = 0; m < 4; ++m) {
            #pragma unroll
            for (int r2 = 0; r2 < 4; ++r2) {
                const int rowB = wr + m * 16 + (l4 << 2) + r2;
                float v = acc[m][n][r2] * (1.0f / 512.0f) + bcol * rinvv[m * 4 + r2];
                v = fmaxf(v, 0.0f);
                am[m * 4 + r2] = fmaxf(am[m * 4 + r2], v);
                cst[rowB * 136 + colB] = (f16)v;
            }
        }
    }
    __syncthreads();
    {
        f16* Cw; int csub;
        if (n0 < CB) { Cw = c0; csub = n0; } else { Cw = c1; csub = n0 - CB; }
        #pragma unroll
        for (int i = 0; i < 8; ++i) {
            int rowB = wid * 32 + i * 4 + l4;
            f16x8 vv = *(const f16x8*)&cst[rowB * 136 + l15 * 8];
            *(f16x8*)&Cw[(size_t)(m0 + rowB) * CB + csub + l15 * 8] = vv;
        }
    }
    if (recAmax) {
        #pragma unroll
        for (int i = 0; i < 16; ++i) {
            float a = am[i];
            a = fmaxf(a, __shfl_xor(a, 1));
            a = fmaxf(a, __shfl_xor(a, 2));
            a = fmaxf(a, __shfl_xor(a, 4));
            a = fmaxf(a, __shfl_xor(a, 8));
            if (l15 == 0) {
                int rowB = wr + (i >> 2) * 16 + (l4 << 2) + (i & 3);
                atomicMax((unsigned int*)&amaxR[rsOff + m0 + rowB],
                          __float_as_uint(a * rvv[i]));
            }
        }
    }
}

// ---- pooling stage 1: deterministic segmented partial sums ----
__global__ __launch_bounds__(256) void pool1_k(
    const f16* __restrict__ h00, const f16* __restrict__ h01,
    const f16* __restrict__ h10, const f16* __restrict__ h11,
    const float* __restrict__ rs,
    const int* __restrict__ goff, float* __restrict__ partial, int half) {
    int g = blockIdx.x, c = blockIdx.y, s = blockIdx.z;
    int t = threadIdx.x;
    int col = c * 256 + t;
    int cb = col >= CB;
    int cc = cb ? col - CB : col;
    int i0 = goff[g], i1 = goff[g + 1];
    int len = i1 - i0;
    int s0 = i0 + (int)(((long long)len * s) / PSEG);
    int s1 = i0 + (int)(((long long)len * (s + 1)) / PSEG);
    float a = 0.0f;
    for (int i = s0; i < s1; ++i) {
        const f16* base = (i < half) ? (cb ? h10 : h00) : (cb ? h11 : h01);
        int r = (i < half) ? i : i - half;
        a += (float)base[(size_t)r * CB + cc] * rs[i];
    }
    partial[((size_t)(g * PSEG + s)) * HID + col] = a;
}

// ---- pooling stage 2: fixed-order sum of PSEG partials ----
__global__ __launch_bounds__(256) void pool2_k(const float* __restrict__ partial,
                                               float shift, float* __restrict__ pooled) {
    int g = blockIdx.x;
    int col = blockIdx.y * 256 + threadIdx.x;
    float a = 0.0f;
    #pragma unroll
    for (int s = 0; s < PSEG; ++s)
        a += partial[((size_t)(g * PSEG + s)) * HID + col];
    pooled[g * HID + col] = a * shift;
}

__global__ __launch_bounds__(512) void final_mm_k(const float* __restrict__ pooled,
                                                  const int* __restrict__ goff,
                                                  const float* __restrict__ Wf,
                                                  const float* __restrict__ bf,
                                                  float* __restrict__ out) {
    __shared__ float ps[HID];
    int g = blockIdx.x;
    int t = threadIdx.x;
    float inv = 1.0f / fmaxf((float)(goff[g + 1] - goff[g]), 1.0f);
    for (int k = t; k < HID; k += 512) ps[k] = pooled[g * HID + k] * inv;
    __syncthreads();
    float acc = bf[t];
    for (int k = 0; k < HID; ++k) acc += ps[k] * Wf[(size_t)k * EMB + t];
    out[(size_t)g * EMB + t] = acc;
}

__global__ void sentinel_k(float* __restrict__ out, int n, float v) {
    int i = blockIdx.x * 256 + threadIdx.x;
    if (i < n) out[i] = v;
}

// ---------------- launch ----------------
extern "C" void kernel_launch(void* const* d_in, const int* in_sizes, int n_in,
                              void* d_out, int out_size, void* d_ws, size_t ws_size,
                              hipStream_t stream) {
    const float* x    = (const float*)d_in[0];
    const int*   ei   = (const int*)d_in[1];
    const int*   batch= (const int*)d_in[2];
    const float* Wp   = (const float*)d_in[3];
    const float* bp   = (const float*)d_in[4];
    const float* W1   = (const float*)d_in[5];
    const float* b1   = (const float*)d_in[6];
    const float* W2   = (const float*)d_in[7];
    const float* b2   = (const float*)d_in[8];
    const float* Wf   = (const float*)d_in[9];
    const float* bf   = (const float*)d_in[10];
    float* out = (float*)d_out;

    const int nreal = in_sizes[0] / FIN;              // 100000
    const int E     = in_sizes[1] / 2;                // 200000
    const int npad  = ((nreal + 511) / 512) * 512;    // 100352
    const int half  = npad / 2;                       // 50176 = 392 tiles of 128
    const size_t slotsz = (size_t)half * CB;          // f16 elements per slot

    char* p = (char*)d_ws;
    auto alloc = [&](size_t bytes) -> char* {
        char* r = p; p += (bytes + 511) & ~(size_t)511; return r;
    };
    f16* slot[6];
    for (int i = 0; i < 6; ++i) slot[i] = (f16*)alloc(slotsz * sizeof(f16));
    f16*   wt   = (f16*)  alloc((size_t)2 * HID * HID * sizeof(f16));
    float* rsA  = (float*)alloc((size_t)npad * sizeof(float));
    float* rsB  = (float*)alloc((size_t)npad * sizeof(float));
    float* amaxR= (float*)alloc((size_t)npad * sizeof(float));
    int*   rp   = (int*)  alloc((size_t)(npad + 1) * sizeof(int));
    int*   csr  = (int*)  alloc((size_t)E * sizeof(int));
    float* wp1  = (float*)alloc((size_t)6 * HID * sizeof(float));
    float* wp1p = (float*)alloc((size_t)WPSEG * 6 * HID * sizeof(float));
    int*   goff = (int*)  alloc((size_t)(NG + 1) * sizeof(int));
    float* pooled = (float*)alloc((size_t)NG * HID * sizeof(float));
    float* partial = (float*)alloc((size_t)NG * PSEG * HID * sizeof(float));
    char*  zstart = p;
    int*   deg  = (int*)  alloc((size_t)npad * sizeof(int));
    int*   cur  = (int*)  alloc((size_t)npad * sizeof(int));
    size_t zbytes = (size_t)(p - zstart);
    size_t need  = (size_t)(p - (char*)d_ws);

    if (need > ws_size) {
        sentinel_k<<<(out_size + 255) / 256, 256, 0, stream>>>(out, out_size, (float)(ws_size >> 20));
        return;
    }

    hipMemsetAsync(zstart, 0, zbytes, stream);

    count_deg_k  <<<(E + 255) / 256, 256, 0, stream>>>(ei, deg, E);
    goff_k       <<<1, 128, 0, stream>>>(batch, goff, nreal);
    scan_rowptr_k<<<1, 1024, 0, stream>>>(deg, rp, cur, nreal);
    scatter_k    <<<(E + 255) / 256, 256, 0, stream>>>(ei, cur, csr, E);
    sort_csr_k   <<<(nreal + 255) / 256, 256, 0, stream>>>(rp, csr, nreal);

    make_wp1_part_k<<<dim3(3, WPSEG), 256, 0, stream>>>(Wp, bp, W1, wp1p);
    make_wp1_red_k <<<3, 256, 0, stream>>>(wp1p, wp1);

    // h slots: h00,h01 = col0 halves; h10,h11 = col1 halves; f0,f1 spare
    f16 *h00 = slot[0], *h01 = slot[1], *h10 = slot[2], *h11 = slot[3];
    f16 *f0 = slot[4], *f1 = slot[5];

    fused_l0_k<<<npad / 4, 256, 0, stream>>>(x, rp, csr, wp1, b1, h00, h01, h10, h11, rsA, nreal, half);

    const int nwg = (half / 128) * (HID / 128);   // 392*6 = 2352

    // layer 0 second matmul (W2[0]): row-half rotation, records amax
    convert_layer_k<<<dim3(HID / 64, HID / 64, 2), 256, 0, stream>>>(W1, W2, wt);
    hipMemsetAsync(amaxR, 0, (size_t)npad * sizeof(float), stream);
    gemm_seg_k<<<nwg, 256, 0, stream>>>(h00, h10, f0, f1, rsA, 0, 1.0f,
                                        wt + (size_t)HID * HID, b2, amaxR, 1);
    gemm_seg_k<<<nwg, 256, 0, stream>>>(h01, h11, h00, h10, rsA, half, 1.0f,
                                        wt + (size_t)HID * HID, b2, amaxR, 1);
    { f16 *n00 = f0, *n10 = f1, *n01 = h00, *n11 = h10, *nf0 = h01, *nf1 = h11;
      h00 = n00; h10 = n10; h01 = n01; h11 = n11; f0 = nf0; f1 = nf1; }

    float* rcur = rsA;
    float  shift = 8.0f;   // stored h = true / (rcur * shift)

    for (int l = 1; l < NL; ++l) {
        convert_layer_k<<<dim3(HID / 64, HID / 64, 2), 256, 0, stream>>>(
            W1 + (size_t)l * HID * HID, W2 + (size_t)l * HID * HID, wt);
        float* rnew = (rcur == rsA) ? rsB : rsA;
        // agg col0 computes rnew inline from amaxR; agg col1 reads rnew
        aggcol_k<<<npad / 8, 256, 0, stream>>>(h00, h01, f0, f1, rcur, shift, rnew, amaxR,
                                               rp, csr, nreal, half, 1);
        aggcol_k<<<npad / 8, 256, 0, stream>>>(h10, h11, h00, h01, rcur, shift, rnew, amaxR,
                                               rp, csr, nreal, half, 0);
        f16 *g00 = f0, *g01 = f1, *g10 = h00, *g11 = h01, *x0 = h10, *x1 = h11;
        // GEMM1 (W1_l): half0 in(g00,g10)->out(x0,x1); half1 in(g01,g11)->out(g00,g10)
        gemm_seg_k<<<nwg, 256, 0, stream>>>(g00, g10, x0, x1, rnew, 0, 1.0f,
                                            wt, b1 + (size_t)l * HID, amaxR, 0);
        gemm_seg_k<<<nwg, 256, 0, stream>>>(g01, g11, g00, g10, rnew, half, 1.0f,
                                            wt, b1 + (size_t)l * HID, amaxR, 0);
        f16 *z00 = x0, *z10 = x1, *z01 = g00, *z11 = g10;   // free: g01,g11
        // GEMM2 (W2_l): records amax
        hipMemsetAsync(amaxR, 0, (size_t)npad * sizeof(float), stream);
        gemm_seg_k<<<nwg, 256, 0, stream>>>(z00, z10, g01, g11, rnew, 0, 8.0f,
                                            wt + (size_t)HID * HID, b2 + (size_t)l * HID, amaxR, 1);
        gemm_seg_k<<<nwg, 256, 0, stream>>>(z01, z11, z00, z10, rnew, half, 8.0f,
                                            wt + (size_t)HID * HID, b2 + (size_t)l * HID, amaxR, 1);
        h00 = g01; h10 = g11; h01 = z00; h11 = z10; f0 = g00; f1 = g10;
        rcur = rnew;
        shift = 64.0f;
    }

    pool1_k<<<dim3(NG, HID / 256, PSEG), 256, 0, stream>>>(h00, h01, h10, h11, rcur, goff, partial, half);
    pool2_k<<<dim3(NG, HID / 256), 256, 0, stream>>>(partial, shift, pooled);
    final_mm_k<<<NG, 512, 0, stream>>>(pooled, goff, Wf, bf, out);
}

// Round 16
// 6454.410 us; speedup vs baseline: 1.5688x; 1.5688x over previous
//
#include <hip/hip_runtime.h>

#define HID 768
#define EMB 512
#define NG  64
#define FIN 5
#define NL  16
#define CB  384   // column block width (HID/2)
#define PSEG 16   // pooling segments per graph
#define WPSEG 16  // make_wp1 segments

typedef _Float16 f16;
typedef f16   f16x4 __attribute__((ext_vector_type(4)));
typedef f16   f16x8 __attribute__((ext_vector_type(8)));
typedef float f32x4 __attribute__((ext_vector_type(4)));

// ---------------- CSR build ----------------
__global__ void count_deg_k(const int* __restrict__ ei, int* __restrict__ deg, int E) {
    int e = blockIdx.x * 256 + threadIdx.x;
    if (e < E) atomicAdd(&deg[ei[E + e]], 1);
}

// batch is sorted: goff[g] = lower_bound(batch, g); no atomics
__global__ void goff_k(const int* __restrict__ batch, int* __restrict__ goff, int n) {
    int g = threadIdx.x;
    if (g > NG) return;
    if (g == NG) { goff[NG] = n; return; }
    int lo = 0, hi = n;
    while (lo < hi) { int mid = (lo + hi) >> 1; if (batch[mid] < g) lo = mid + 1; else hi = mid; }
    goff[g] = lo;
}

__global__ void scan_rowptr_k(const int* __restrict__ deg, int* __restrict__ rp,
                              int* __restrict__ cur, int n) {
    __shared__ int wsum[16];
    __shared__ int carry;
    int t = threadIdx.x, lane = t & 63, w = t >> 6;
    if (t == 0) carry = 0;
    __syncthreads();
    for (int base = 0; base < n; base += 4096) {
        int v[4]; int s = 0;
        #pragma unroll
        for (int q = 0; q < 4; ++q) { int i = base + t * 4 + q; v[q] = (i < n) ? deg[i] : 0; s += v[q]; }
        int tot = s;
        int sc = tot;
        #pragma unroll
        for (int off = 1; off < 64; off <<= 1) { int u = __shfl_up(sc, off); if (lane >= off) sc += u; }
        if (lane == 63) wsum[w] = sc;
        __syncthreads();
        if (t < 16) {
            int xw = wsum[t];
            #pragma unroll
            for (int off = 1; off < 16; off <<= 1) { int u = __shfl_up(xw, off); if (t >= off) xw += u; }
            wsum[t] = xw;
        }
        __syncthreads();
        int woff = (w > 0) ? wsum[w - 1] : 0;
        int excl = carry + woff + sc - tot;
        #pragma unroll
        for (int q = 0; q < 4; ++q) { int i = base + t * 4 + q; if (i < n) { rp[i] = excl; cur[i] = excl; } excl += v[q]; }
        __syncthreads();
        if (t == 0) carry += wsum[15];
        __syncthreads();
    }
    if (t == 0) rp[n] = carry;
}

__global__ void scatter_k(const int* __restrict__ ei, int* __restrict__ cur,
                          int* __restrict__ csr, int E) {
    int e = blockIdx.x * 256 + threadIdx.x;
    if (e < E) { int d = ei[E + e]; int pos = atomicAdd(&cur[d], 1); csr[pos] = ei[e]; }
}

// canonicalize neighbor order (atomic scatter order varies call-to-call)
__global__ void sort_csr_k(const int* __restrict__ rp, int* __restrict__ csr, int n) {
    int i = blockIdx.x * 256 + threadIdx.x;
    if (i >= n) return;
    int e0 = rp[i], e1 = rp[i + 1];
    for (int a = e0 + 1; a < e1; ++a) {
        int v = csr[a];
        int b = a - 1;
        while (b >= e0 && csr[b] > v) { csr[b + 1] = csr[b]; --b; }
        csr[b + 1] = v;
    }
}

// ---- batched weight convert: layers l0..l0+3, W[k][n] fp32 -> wt4[li*2+z][n][k] fp16*64 ----
__global__ void convert_batch_k(const float* __restrict__ W1, const float* __restrict__ W2,
                                f16* __restrict__ wt4, int l0) {
    __shared__ float tile[64][65];
    int li = blockIdx.z >> 1, which = blockIdx.z & 1;
    const float* src = (which ? W2 : W1) + (size_t)(l0 + li) * HID * HID;
    f16* dst = wt4 + (size_t)(li * 2 + which) * HID * HID;
    int k0 = blockIdx.x * 64, n0 = blockIdx.y * 64;
    int t = threadIdx.x;
    #pragma unroll 4
    for (int i = 0; i < 16; ++i) {
        int r = (t >> 6) + i * 4;
        tile[r][t & 63] = src[(size_t)(k0 + r) * HID + n0 + (t & 63)];
    }
    __syncthreads();
    #pragma unroll 4
    for (int i = 0; i < 16; ++i) {
        int r = (t >> 6) + i * 4;
        dst[(size_t)(n0 + r) * HID + k0 + (t & 63)] = (f16)(tile[t & 63][r] * 64.0f);
    }
}

// ---- layer-0 folding, 2-stage deterministic ----
__global__ void make_wp1_part_k(const float* __restrict__ Wp, const float* __restrict__ bp,
                                const float* __restrict__ W1_0, float* __restrict__ part) {
    int nn = blockIdx.x * 256 + threadIdx.x;
    int s = blockIdx.y;
    if (nn >= HID) return;
    float acc[6] = {0, 0, 0, 0, 0, 0};
    int j0 = s * (HID / WPSEG), j1 = j0 + (HID / WPSEG);
    for (int j = j0; j < j1; ++j) {
        float wj = W1_0[(size_t)j * HID + nn];
        #pragma unroll
        for (int k = 0; k < FIN; ++k) acc[k] += Wp[k * HID + j] * wj;
        acc[5] += bp[j] * wj;
    }
    #pragma unroll
    for (int k = 0; k < 6; ++k) part[((size_t)s * 6 + k) * HID + nn] = acc[k];
}

__global__ void make_wp1_red_k(const float* __restrict__ part, float* __restrict__ wp1) {
    int nn = blockIdx.x * 256 + threadIdx.x;
    if (nn >= HID) return;
    #pragma unroll
    for (int k = 0; k < 6; ++k) {
        float a = 0.0f;
        #pragma unroll
        for (int s = 0; s < WPSEG; ++s) a += part[((size_t)s * 6 + k) * HID + nn];
        wp1[k * HID + nn] = a;
    }
}

__device__ __forceinline__ void row_scale(float amax, float& sc, float& rs) {
    int ex = 10;
    if (amax > 0.0f) frexpf(amax, &ex);
    int sh = 10 - ex;
    sh = sh > 120 ? 120 : (sh < -120 ? -120 : sh);
    sc = ldexpf(1.0f, sh);
    rs = ldexpf(1.0f, -sh);
}

// ---- fused layer0: z = relu(xagg@wp1 + (deg+1)*bpW1 + b1_0); writes 4 h-slots ----
__global__ __launch_bounds__(256) void fused_l0_k(
    const float* __restrict__ x, const int* __restrict__ rp, const int* __restrict__ csr,
    const float* __restrict__ wp1, const float* __restrict__ b1_0,
    f16* __restrict__ h00, f16* __restrict__ h01,   // col0: half0, half1
    f16* __restrict__ h10, f16* __restrict__ h11,   // col1: half0, half1
    float* __restrict__ rs_out, int nreal, int half) {
    __shared__ float w[7 * HID];
    for (int idx = threadIdx.x; idx < 7 * HID; idx += 256)
        w[idx] = (idx < 6 * HID) ? wp1[idx] : b1_0[idx - 6 * HID];
    __syncthreads();
    int node = blockIdx.x * 4 + (threadIdx.x >> 6);
    int lane = threadIdx.x & 63;
    int cblk = lane >> 5, ll = lane & 31;
    f16* base;
    int rloc;
    if (node < half) { base = cblk ? h10 : h00; rloc = node; }
    else             { base = cblk ? h11 : h01; rloc = node - half; }
    f16* orow = base + (size_t)rloc * CB + ll * 12;
    if (node >= nreal) {
        #pragma unroll
        for (int t = 0; t < 12; ++t) orow[t] = (f16)0.0f;
        if (lane == 0) rs_out[node] = 1.0f;
        return;
    }
    int e0 = rp[node], e1 = rp[node + 1];
    float xa[FIN];
    #pragma unroll
    for (int k = 0; k < FIN; ++k) xa[k] = x[(size_t)node * FIN + k];
    for (int e = e0; e < e1; ++e) {
        int j = csr[e];
        #pragma unroll
        for (int k = 0; k < FIN; ++k) xa[k] += x[(size_t)j * FIN + k];
    }
    float dp1 = (float)(e1 - e0 + 1);
    float a[12];
    #pragma unroll
    for (int t = 0; t < 12; ++t) {
        int c = lane * 12 + t;
        float v = w[5 * HID + c] * dp1 + w[6 * HID + c];
        #pragma unroll
        for (int k = 0; k < FIN; ++k) v += xa[k] * w[k * HID + c];
        a[t] = fmaxf(v, 0.0f);
    }
    float amax = 0.0f;
    #pragma unroll
    for (int t = 0; t < 12; ++t) amax = fmaxf(amax, fabsf(a[t]));
    #pragma unroll
    for (int off = 32; off; off >>= 1) amax = fmaxf(amax, __shfl_xor(amax, off));
    float sc, rs;
    row_scale(amax, sc, rs);
    if (lane == 0) rs_out[node] = rs;
    #pragma unroll
    for (int t = 0; t < 12; ++t) orow[t] = (f16)(a[t] * sc);
}

// ---- aggcol: one column block (2 row-half slots in, 2 out).
// computeScale=1 (col0 pass): also derive fresh per-row scale rsOut from amaxR inline ----
__global__ __launch_bounds__(256) void aggcol_k(
    const f16* __restrict__ s0, const f16* __restrict__ s1,
    f16* __restrict__ d0, f16* __restrict__ d1,
    const float* __restrict__ rsIn, float inShift,
    float* __restrict__ rsOut, const float* __restrict__ amaxR,
    const int* __restrict__ rp, const int* __restrict__ csr, int nreal, int half,
    int computeScale) {
    int node = blockIdx.x * 8 + (threadIdx.x >> 5);
    int l = threadIdx.x & 31;
    f16* orow = (node < half ? d0 + (size_t)node * CB : d1 + (size_t)(node - half) * CB) + l * 12;
    if (node >= nreal) {
        #pragma unroll
        for (int t = 0; t < 12; ++t) orow[t] = (f16)0.0f;
        if (computeScale && l == 0) rsOut[node] = 1.0f;
        return;
    }
    int e0 = rp[node], e1 = rp[node + 1];
    float invOut;
    if (computeScale) {
        float M = amaxR[node];
        for (int e = e0; e < e1; ++e) M = fmaxf(M, amaxR[csr[e]]);
        float r = 1.0f;
        if (M > 0.0f) {
            int ex; frexpf(M, &ex);
            int sh = ex - 9;                  // M / 2^sh in [256,512)
            sh = sh > 120 ? 120 : (sh < -120 ? -120 : sh);
            r = ldexpf(1.0f, sh);
        }
        if (l == 0) rsOut[node] = r;
        invOut = 1.0f / r;
    } else {
        invOut = 1.0f / rsOut[node];
    }
    float a[12];
    {
        float f = rsIn[node] * inShift * invOut;
        const f16* srow = (node < half ? s0 + (size_t)node * CB : s1 + (size_t)(node - half) * CB);
        const f16x4* p = (const f16x4*)(srow + l * 12);
        f16x4 v0 = p[0], v1 = p[1], v2 = p[2];
        #pragma unroll
        for (int t = 0; t < 4; ++t) {
            a[t] = (float)v0[t] * f; a[4 + t] = (float)v1[t] * f; a[8 + t] = (float)v2[t] * f;
        }
    }
    for (int e = e0; e < e1; ++e) {
        int j = csr[e];
        float f = rsIn[j] * inShift * invOut;
        const f16* srow = (j < half ? s0 + (size_t)j * CB : s1 + (size_t)(j - half) * CB);
        const f16x4* p = (const f16x4*)(srow + l * 12);
        f16x4 v0 = p[0], v1 = p[1], v2 = p[2];
        #pragma unroll
        for (int t = 0; t < 4; ++t) {
            a[t] += (float)v0[t] * f; a[4 + t] += (float)v1[t] * f; a[8 + t] += (float)v2[t] * f;
        }
    }
    f16x4 o0, o1, o2;
    #pragma unroll
    for (int t = 0; t < 4; ++t) {
        o0[t] = (f16)a[t]; o1[t] = (f16)a[4 + t]; o2[t] = (f16)a[8 + t];
    }
    f16x4* op = (f16x4*)orow;
    op[0] = o0; op[1] = o1; op[2] = o2;
}

// ---- GEMM (round-13 proven best): 128x128 tile, BK=64, A depth 3 / B depth 2
// (80 KB LDS, 2 blocks/CU). FIFO-exact counted vmcnt (steady: wait_A=8, wait_B=12),
// T2 involution swizzle, T5 setprio, XCD-swizzled flat grid, LDS-staged C epilogue. ----
__global__ __launch_bounds__(256) void gemm_seg_k(
    const f16* __restrict__ a0, const f16* __restrict__ a1,
    f16* __restrict__ c0, f16* __restrict__ c1,
    const float* __restrict__ rs, int rsOff, float shiftIn,
    const f16* __restrict__ wt, const float* __restrict__ bias,
    float* __restrict__ amaxR, int recAmax) {
    __shared__ f16 lds[40960];            // Abuf[3] @ 0/8192/16384, Bbuf[2] @ 24576/32768
    const int tid = threadIdx.x;
    const int lane = tid & 63;
    const int wid = tid >> 6;

    // bijective XCD swizzle (ERRATA #11 form), n-fastest within chunk
    const int nwg = gridDim.x;
    const int q = nwg >> 3, r = nwg & 7;
    const int xcd = blockIdx.x & 7, loc = blockIdx.x >> 3;
    const int id2 = (xcd < r ? xcd * (q + 1) : r * (q + 1) + (xcd - r) * q) + loc;
    const int m0 = (id2 / 6) * 128;
    const int n0 = (id2 % 6) * 128;

    const int wr = (wid >> 1) * 64;
    const int wc = (wid & 1) * 64;
    const int lrow = lane >> 3;                 // 0..7
    const int usrc = (lane & 7) ^ lrow;         // inverse-swizzled 16B unit for staging src
    const int l15 = lane & 15, l4 = lane >> 4;

    auto stageA = [&](int kt, int buf) {
        const f16* abase = (kt < 6) ? a0 : a1;
        const int kb = (kt < 6 ? kt : kt - 6) * 64;
        f16* As = lds + buf * 8192;
        #pragma unroll
        for (int i = 0; i < 4; ++i) {
            int chunk = i * 4 + wid;            // wave-uniform
            int row = chunk * 8 + lrow;
            const f16* ga = abase + (size_t)(m0 + row) * CB + kb + usrc * 8;
            __builtin_amdgcn_global_load_lds(
                (const __attribute__((address_space(1))) void*)ga,
                (__attribute__((address_space(3))) void*)(As + chunk * 512), 16, 0, 0);
        }
    };
    auto stageB = [&](int kt, int buf) {
        const int kw = kt * 64;
        f16* Bs = lds + 24576 + buf * 8192;
        #pragma unroll
        for (int i = 0; i < 4; ++i) {
            int chunk = i * 4 + wid;
            int row = chunk * 8 + lrow;
            const f16* gb = wt + (size_t)(n0 + row) * HID + kw + usrc * 8;
            __builtin_amdgcn_global_load_lds(
                (const __attribute__((address_space(1))) void*)gb,
                (__attribute__((address_space(3))) void*)(Bs + chunk * 512), 16, 0, 0);
        }
    };

    f32x4 acc[4][4];
    #pragma unroll
    for (int m = 0; m < 4; ++m)
        #pragma unroll
        for (int n = 0; n < 4; ++n) acc[m][n] = (f32x4){0.f, 0.f, 0.f, 0.f};

    // prologue: A0, B0, A1 (12 loads; FIFO order A(t),B(t),A(t+1) established)
    stageA(0, 0);
    stageB(0, 0);
    stageA(1, 1);

    #pragma unroll
    for (int t = 0; t < 12; ++t) {
        const f16* Ac = lds + (t % 3) * 8192;
        const f16* Bc = lds + 24576 + (t & 1) * 8192;
        // wait_A: drain A(t). steady leaves {B(t), A(t+1)} = 8; t=11 leaves {B(11)} = 4
        if (t < 11) asm volatile("s_waitcnt vmcnt(8)" ::: "memory");
        else        asm volatile("s_waitcnt vmcnt(4)" ::: "memory");
        __builtin_amdgcn_s_barrier();
        __builtin_amdgcn_sched_barrier(0);
        // A fragments (swizzled read)
        f16x8 af[4][2];
        #pragma unroll
        for (int m = 0; m < 4; ++m) {
            int rowH = wr + m * 16 + l15;
            int sw = rowH & 7;
            #pragma unroll
            for (int kk = 0; kk < 2; ++kk) {
                int u = kk * 4 + l4;
                af[m][kk] = *(const f16x8*)(Ac + rowH * 64 + ((u ^ sw) << 3));
            }
        }
        // prefetch issues (both buffers' step-(t-1) readers crossed the barrier above)
        if (t < 11) stageB(t + 1, (t + 1) & 1);
        if (t < 10) stageA(t + 2, (t + 2) % 3);
        // wait_B: drain B(t). steady leaves {A(t+1),B(t+1),A(t+2)} = 12;
        // t=10 leaves {A(11),B(11)} = 8; t=11 leaves {} = 0
        if (t < 10)      asm volatile("s_waitcnt vmcnt(12)" ::: "memory");
        else if (t == 10) asm volatile("s_waitcnt vmcnt(8)" ::: "memory");
        else             asm volatile("s_waitcnt vmcnt(0)" ::: "memory");
        __builtin_amdgcn_s_barrier();
        __builtin_amdgcn_sched_barrier(0);
        // B fragments + MFMA cluster
        f16x8 bfr[4][2];
        #pragma unroll
        for (int n = 0; n < 4; ++n) {
            int rowB = wc + n * 16 + l15;
            int sw = rowB & 7;
            #pragma unroll
            for (int kk = 0; kk < 2; ++kk) {
                int u = kk * 4 + l4;
                bfr[n][kk] = *(const f16x8*)(Bc + rowB * 64 + ((u ^ sw) << 3));
            }
        }
        __builtin_amdgcn_s_setprio(1);
        #pragma unroll
        for (int kk = 0; kk < 2; ++kk)
            #pragma unroll
            for (int m = 0; m < 4; ++m)
                #pragma unroll
                for (int n = 0; n < 4; ++n)
                    acc[m][n] = __builtin_amdgcn_mfma_f32_16x16x32_f16(af[m][kk], bfr[n][kk], acc[m][n], 0, 0, 0);
        __builtin_amdgcn_s_setprio(0);
    }
    __syncthreads();

    // ---- epilogue: per-lane row scales (registers), bias+relu+amax, stage C in LDS
    // [128][136], coalesced f16x8 stores ----
    float rvv[16], rinvv[16];
    #pragma unroll
    for (int m = 0; m < 4; ++m)
        #pragma unroll
        for (int r2 = 0; r2 < 4; ++r2) {
            int rowB = wr + m * 16 + (l4 << 2) + r2;
            float rv = rs[rsOff + m0 + rowB] * shiftIn * 8.0f;
            rvv[m * 4 + r2] = rv;
            rinvv[m * 4 + r2] = 1.0f / rv;
        }
    f16* cst = lds;   // aliases buffers; safe after barrier
    float am[16];
    #pragma unroll
    for (int i = 0; i < 16; ++i) am[i] = 0.0f;
    #pragma unroll
    for (int n = 0; n < 4; ++n) {
        const int colB = wc + n * 16 + l15;
        const float bcol = bias[n0 + colB];
        #pragma unroll
        for (int m = 0; m < 4; ++m) {
            #pragma unroll
            for (int r2 = 0; r2 < 4; ++r2) {
                const int rowB = wr + m * 16 + (l4 << 2) + r2;
                float v = acc[m][n][r2] * (1.0f / 512.0f) + bcol * rinvv[m * 4 + r2];
                v = fmaxf(v, 0.0f);
                am[m * 4 + r2] = fmaxf(am[m * 4 + r2], v);
                cst[rowB * 136 + colB] = (f16)v;
            }
        }
    }
    __syncthreads();
    {
        f16* Cw; int csub;
        if (n0 < CB) { Cw = c0; csub = n0; } else { Cw = c1; csub = n0 - CB; }
        #pragma unroll
        for (int i = 0; i < 8; ++i) {
            int rowB = wid * 32 + i * 4 + l4;
            f16x8 vv = *(const f16x8*)&cst[rowB * 136 + l15 * 8];
            *(f16x8*)&Cw[(size_t)(m0 + rowB) * CB + csub + l15 * 8] = vv;
        }
    }
    if (recAmax) {
        #pragma unroll
        for (int i = 0; i < 16; ++i) {
            float a = am[i];
            a = fmaxf(a, __shfl_xor(a, 1));
            a = fmaxf(a, __shfl_xor(a, 2));
            a = fmaxf(a, __shfl_xor(a, 4));
            a = fmaxf(a, __shfl_xor(a, 8));
            if (l15 == 0) {
                int rowB = wr + (i >> 2) * 16 + (l4 << 2) + (i & 3);
                atomicMax((unsigned int*)&amaxR[rsOff + m0 + rowB],
                          __float_as_uint(a * rvv[i]));
            }
        }
    }
}

// ---- pooling stage 1: deterministic segmented partial sums ----
__global__ __launch_bounds__(256) void pool1_k(
    const f16* __restrict__ h00, const f16* __restrict__ h01,
    const f16* __restrict__ h10, const f16* __restrict__ h11,
    const float* __restrict__ rs,
    const int* __restrict__ goff, float* __restrict__ partial, int half) {
    int g = blockIdx.x, c = blockIdx.y, s = blockIdx.z;
    int t = threadIdx.x;
    int col = c * 256 + t;
    int cb = col >= CB;
    int cc = cb ? col - CB : col;
    int i0 = goff[g], i1 = goff[g + 1];
    int len = i1 - i0;
    int s0 = i0 + (int)(((long long)len * s) / PSEG);
    int s1 = i0 + (int)(((long long)len * (s + 1)) / PSEG);
    float a = 0.0f;
    for (int i = s0; i < s1; ++i) {
        const f16* base = (i < half) ? (cb ? h10 : h00) : (cb ? h11 : h01);
        int r = (i < half) ? i : i - half;
        a += (float)base[(size_t)r * CB + cc] * rs[i];
    }
    partial[((size_t)(g * PSEG + s)) * HID + col] = a;
}

// ---- pooling stage 2: fixed-order sum of PSEG partials ----
__global__ __launch_bounds__(256) void pool2_k(const float* __restrict__ partial,
                                               float shift, float* __restrict__ pooled) {
    int g = blockIdx.x;
    int col = blockIdx.y * 256 + threadIdx.x;
    float a = 0.0f;
    #pragma unroll
    for (int s = 0; s < PSEG; ++s)
        a += partial[((size_t)(g * PSEG + s)) * HID + col];
    pooled[g * HID + col] = a * shift;
}

__global__ __launch_bounds__(512) void final_mm_k(const float* __restrict__ pooled,
                                                  const int* __restrict__ goff,
                                                  const float* __restrict__ Wf,
                                                  const float* __restrict__ bf,
                                                  float* __restrict__ out) {
    __shared__ float ps[HID];
    int g = blockIdx.x;
    int t = threadIdx.x;
    float inv = 1.0f / fmaxf((float)(goff[g + 1] - goff[g]), 1.0f);
    for (int k = t; k < HID; k += 512) ps[k] = pooled[g * HID + k] * inv;
    __syncthreads();
    float acc = bf[t];
    for (int k = 0; k < HID; ++k) acc += ps[k] * Wf[(size_t)k * EMB + t];
    out[(size_t)g * EMB + t] = acc;
}

__global__ void sentinel_k(float* __restrict__ out, int n, float v) {
    int i = blockIdx.x * 256 + threadIdx.x;
    if (i < n) out[i] = v;
}

// ---------------- launch ----------------
extern "C" void kernel_launch(void* const* d_in, const int* in_sizes, int n_in,
                              void* d_out, int out_size, void* d_ws, size_t ws_size,
                              hipStream_t stream) {
    const float* x    = (const float*)d_in[0];
    const int*   ei   = (const int*)d_in[1];
    const int*   batch= (const int*)d_in[2];
    const float* Wp   = (const float*)d_in[3];
    const float* bp   = (const float*)d_in[4];
    const float* W1   = (const float*)d_in[5];
    const float* b1   = (const float*)d_in[6];
    const float* W2   = (const float*)d_in[7];
    const float* b2   = (const float*)d_in[8];
    const float* Wf   = (const float*)d_in[9];
    const float* bf   = (const float*)d_in[10];
    float* out = (float*)d_out;

    const int nreal = in_sizes[0] / FIN;              // 100000
    const int E     = in_sizes[1] / 2;                // 200000
    const int npad  = ((nreal + 511) / 512) * 512;    // 100352
    const int half  = npad / 2;                       // 50176 = 392 tiles of 128
    const size_t slotsz = (size_t)half * CB;          // f16 elements per slot

    char* p = (char*)d_ws;
    auto alloc = [&](size_t bytes) -> char* {
        char* r = p; p += (bytes + 511) & ~(size_t)511; return r;
    };
    f16* slot[6];
    for (int i = 0; i < 6; ++i) slot[i] = (f16*)alloc(slotsz * sizeof(f16));
    f16*   wt4  = (f16*)  alloc((size_t)4 * 2 * HID * HID * sizeof(f16));  // 4-layer batch
    float* rsA  = (float*)alloc((size_t)npad * sizeof(float));
    float* rsB  = (float*)alloc((size_t)npad * sizeof(float));
    float* amaxR= (float*)alloc((size_t)npad * sizeof(float));
    int*   rp   = (int*)  alloc((size_t)(npad + 1) * sizeof(int));
    int*   csr  = (int*)  alloc((size_t)E * sizeof(int));
    float* wp1  = (float*)alloc((size_t)6 * HID * sizeof(float));
    float* wp1p = (float*)alloc((size_t)WPSEG * 6 * HID * sizeof(float));
    int*   goff = (int*)  alloc((size_t)(NG + 1) * sizeof(int));
    float* pooled = (float*)alloc((size_t)NG * HID * sizeof(float));
    float* partial = (float*)alloc((size_t)NG * PSEG * HID * sizeof(float));
    char*  zstart = p;
    int*   deg  = (int*)  alloc((size_t)npad * sizeof(int));
    int*   cur  = (int*)  alloc((size_t)npad * sizeof(int));
    size_t zbytes = (size_t)(p - zstart);
    size_t need  = (size_t)(p - (char*)d_ws);

    if (need > ws_size) {
        sentinel_k<<<(out_size + 255) / 256, 256, 0, stream>>>(out, out_size, (float)(ws_size >> 20));
        return;
    }

    hipMemsetAsync(zstart, 0, zbytes, stream);

    count_deg_k  <<<(E + 255) / 256, 256, 0, stream>>>(ei, deg, E);
    goff_k       <<<1, 128, 0, stream>>>(batch, goff, nreal);
    scan_rowptr_k<<<1, 1024, 0, stream>>>(deg, rp, cur, nreal);
    scatter_k    <<<(E + 255) / 256, 256, 0, stream>>>(ei, cur, csr, E);
    sort_csr_k   <<<(nreal + 255) / 256, 256, 0, stream>>>(rp, csr, nreal);

    make_wp1_part_k<<<dim3(3, WPSEG), 256, 0, stream>>>(Wp, bp, W1, wp1p);
    make_wp1_red_k <<<3, 256, 0, stream>>>(wp1p, wp1);

    // h slots: h00,h01 = col0 halves; h10,h11 = col1 halves; f0,f1 spare
    f16 *h00 = slot[0], *h01 = slot[1], *h10 = slot[2], *h11 = slot[3];
    f16 *f0 = slot[4], *f1 = slot[5];

    fused_l0_k<<<npad / 4, 256, 0, stream>>>(x, rp, csr, wp1, b1, h00, h01, h10, h11, rsA, nreal, half);

    const int nwg = (half / 128) * (HID / 128);   // 392*6 = 2352
    const size_t WSZ = (size_t)HID * HID;

    // convert layers 0..3; layer 0 second matmul (W2[0]) with row-half rotation
    convert_batch_k<<<dim3(HID / 64, HID / 64, 8), 256, 0, stream>>>(W1, W2, wt4, 0);
    hipMemsetAsync(amaxR, 0, (size_t)npad * sizeof(float), stream);
    gemm_seg_k<<<nwg, 256, 0, stream>>>(h00, h10, f0, f1, rsA, 0, 1.0f,
                                        wt4 + WSZ, b2, amaxR, 1);
    gemm_seg_k<<<nwg, 256, 0, stream>>>(h01, h11, h00, h10, rsA, half, 1.0f,
                                        wt4 + WSZ, b2, amaxR, 1);
    { f16 *n00 = f0, *n10 = f1, *n01 = h00, *n11 = h10, *nf0 = h01, *nf1 = h11;
      h00 = n00; h10 = n10; h01 = n01; h11 = n11; f0 = nf0; f1 = nf1; }

    float* rcur = rsA;
    float  shift = 8.0f;   // stored h = true / (rcur * shift)

    for (int l = 1; l < NL; ++l) {
        if ((l & 3) == 0)   // convert layers l..l+3
            convert_batch_k<<<dim3(HID / 64, HID / 64, 8), 256, 0, stream>>>(W1, W2, wt4, l);
        const f16* wtl = wt4 + (size_t)(l & 3) * 2 * WSZ;
        float* rnew = (rcur == rsA) ? rsB : rsA;
        // agg col0 computes rnew inline from amaxR; agg col1 reads rnew
        aggcol_k<<<npad / 8, 256, 0, stream>>>(h00, h01, f0, f1, rcur, shift, rnew, amaxR,
                                               rp, csr, nreal, half, 1);
        aggcol_k<<<npad / 8, 256, 0, stream>>>(h10, h11, h00, h01, rcur, shift, rnew, amaxR,
                                               rp, csr, nreal, half, 0);
        f16 *g00 = f0, *g01 = f1, *g10 = h00, *g11 = h01, *x0 = h10, *x1 = h11;
        // GEMM1 (W1_l): half0 in(g00,g10)->out(x0,x1); half1 in(g01,g11)->out(g00,g10)
        gemm_seg_k<<<nwg, 256, 0, stream>>>(g00, g10, x0, x1, rnew, 0, 1.0f,
                                            wtl, b1 + (size_t)l * HID, amaxR, 0);
        gemm_seg_k<<<nwg, 256, 0, stream>>>(g01, g11, g00, g10, rnew, half, 1.0f,
                                            wtl, b1 + (size_t)l * HID, amaxR, 0);
        f16 *z00 = x0, *z10 = x1, *z01 = g00, *z11 = g10;   // free: g01,g11
        // GEMM2 (W2_l): records amax
        hipMemsetAsync(amaxR, 0, (size_t)npad * sizeof(float), stream);
        gemm_seg_k<<<nwg, 256, 0, stream>>>(z00, z10, g01, g11, rnew, 0, 8.0f,
                                            wtl + WSZ, b2 + (size_t)l * HID, amaxR, 1);
        gemm_seg_k<<<nwg, 256, 0, stream>>>(z01, z11, z00, z10, rnew, half, 8.0f,
                                            wtl + WSZ, b2 + (size_t)l * HID, amaxR, 1);
        h00 = g01; h10 = g11; h01 = z00; h11 = z10; f0 = g00; f1 = g10;
        rcur = rnew;
        shift = 64.0f;
    }

    pool1_k<<<dim3(NG, HID / 256, PSEG), 256, 0, stream>>>(h00, h01, h10, h11, rcur, goff, partial, half);
    pool2_k<<<dim3(NG, HID / 256), 256, 0, stream>>>(partial, shift, pooled);
    final_mm_k<<<NG, 512, 0, stream>>>(pooled, goff, Wf, bf, out);
}